// Round 1
// baseline (546.366 us; speedup 1.0000x reference)
//
#include <hip/hip_runtime.h>

#define B_ 8
#define T_ 4096
#define C_ 1024
#define H_ 128

using bf16x8 = __attribute__((ext_vector_type(8))) __bf16;
using f32x4  = __attribute__((ext_vector_type(4))) float;

__device__ __forceinline__ unsigned short f2bf(float f) {
    union { float f; unsigned u; } v; v.f = f;
    unsigned u = v.u;
    u += 0x7FFF + ((u >> 16) & 1);   // round-to-nearest-even
    return (unsigned short)(u >> 16);
}

// ---------------- kernel 1: weights -> bf16, transposed wt[w][h][c] ----------------
__global__ __launch_bounds__(256) void wt_kernel(const float* __restrict__ Wq,
                                                 const float* __restrict__ Wk,
                                                 const float* __restrict__ Wv,
                                                 unsigned short* __restrict__ wt) {
    int idx = blockIdx.x * 256 + threadIdx.x;       // 3*1024*128 total
    int w = idx / (C_ * H_);
    int r = idx - w * (C_ * H_);
    int c = r >> 7;          // / H_
    int h = r & (H_ - 1);
    const float* W = (w == 0) ? Wq : (w == 1) ? Wk : Wv;
    wt[((size_t)w * H_ + h) * C_ + c] = f2bf(W[r]);
}

// ---------------- kernel 2: QKV projection ----------------
// out tile 128x128 per block; grid (3, 256): x = which weight (q,k,v), y = m-tile.
// q,k stored [m][h] bf16; v stored transposed vt[b][h][t] bf16.
#define PLDA 40   // 32 + 8 pad (16B) -> 2-way-only bank aliasing on b128 reads
__global__ __launch_bounds__(256) void proj_kernel(
        const float* __restrict__ x, const unsigned short* __restrict__ wt,
        unsigned short* __restrict__ q, unsigned short* __restrict__ k,
        unsigned short* __restrict__ vt) {
    __shared__ unsigned short Xs[128 * PLDA];
    __shared__ unsigned short Ws[128 * PLDA];
    const int widx = blockIdx.x;
    const int mt   = blockIdx.y;
    const int tid  = threadIdx.x;
    const int wave = tid >> 6, lane = tid & 63, quad = lane >> 4, l16 = lane & 15;
    const int r0 = (wave >> 1) * 64;      // wave's row offset in 128-tile
    const int c0 = (wave & 1) * 64;       // wave's col offset
    const size_t m0 = (size_t)mt * 128;
    const unsigned short* wtw = wt + (size_t)widx * H_ * C_;

    f32x4 acc[4][4];
    #pragma unroll
    for (int mi = 0; mi < 4; mi++)
        #pragma unroll
        for (int ni = 0; ni < 4; ni++)
            acc[mi][ni] = (f32x4){0.f, 0.f, 0.f, 0.f};

    for (int k0 = 0; k0 < C_; k0 += 32) {
        __syncthreads();
        // stage X tile 128x32 fp32 -> bf16 (convert in registers)
        #pragma unroll
        for (int f = 0; f < 4; f++) {
            int g   = f * 256 + tid;       // float4 id; 8 per row
            int row = g >> 3;
            int col = (g & 7) * 4;
            float4 xv = *(const float4*)(x + (m0 + row) * C_ + k0 + col);
            ushort4 pk;
            pk.x = f2bf(xv.x); pk.y = f2bf(xv.y); pk.z = f2bf(xv.z); pk.w = f2bf(xv.w);
            *(ushort4*)&Xs[row * PLDA + col] = pk;
        }
        // stage Wt tile [n=128][k=32] bf16 (already transposed in global)
        #pragma unroll
        for (int f = 0; f < 2; f++) {
            int g   = f * 256 + tid;       // 8-elem group id; 4 per row
            int row = g >> 2;
            int col = (g & 3) * 8;
            uint4 wv = *(const uint4*)(wtw + (size_t)row * C_ + k0 + col);
            *(uint4*)&Ws[row * PLDA + col] = wv;
        }
        __syncthreads();
        bf16x8 af[4], bfr[4];
        #pragma unroll
        for (int mi = 0; mi < 4; mi++)
            af[mi] = *(const bf16x8*)&Xs[(r0 + mi * 16 + l16) * PLDA + quad * 8];
        #pragma unroll
        for (int ni = 0; ni < 4; ni++)
            bfr[ni] = *(const bf16x8*)&Ws[(c0 + ni * 16 + l16) * PLDA + quad * 8];
        #pragma unroll
        for (int mi = 0; mi < 4; mi++)
            #pragma unroll
            for (int ni = 0; ni < 4; ni++)
                acc[mi][ni] = __builtin_amdgcn_mfma_f32_16x16x32_bf16(
                                  af[mi], bfr[ni], acc[mi][ni], 0, 0, 0);
    }

    // epilogue: C/D layout col=lane&15, row=quad*4+reg
    if (widx < 2) {
        unsigned short* dst = (widx == 0) ? q : k;
        #pragma unroll
        for (int mi = 0; mi < 4; mi++)
            #pragma unroll
            for (int ni = 0; ni < 4; ni++)
                #pragma unroll
                for (int r = 0; r < 4; r++) {
                    size_t row = m0 + r0 + mi * 16 + quad * 4 + r;
                    int col = c0 + ni * 16 + l16;
                    dst[row * H_ + col] = f2bf(acc[mi][ni][r]);
                }
    } else {
        #pragma unroll
        for (int mi = 0; mi < 4; mi++)
            #pragma unroll
            for (int ni = 0; ni < 4; ni++)
                #pragma unroll
                for (int r = 0; r < 4; r++) {
                    size_t m = m0 + r0 + mi * 16 + quad * 4 + r;
                    int bb = (int)(m >> 12);          // / T_
                    int t  = (int)(m & (T_ - 1));
                    int h  = c0 + ni * 16 + l16;
                    vt[((size_t)bb * H_ + h) * T_ + t] = f2bf(acc[mi][ni][r]);
                }
    }
}

// ---------------- kernel 3: causal flash attention ----------------
// BM=BN=64, 4 waves x 16 q-rows. Q frags hoisted to regs; K reuses Q's LDS buffer.
#define FLDQ 136  // 128 + 8
#define FLDP 72   // 64 + 8
__global__ __launch_bounds__(256) void flash_kernel(
        const unsigned short* __restrict__ q,
        const unsigned short* __restrict__ kmat,
        const unsigned short* __restrict__ vt,
        float* __restrict__ out) {
    __shared__ unsigned short KQs[64 * FLDQ];  // Q first, then K tiles
    __shared__ unsigned short Vs[H_ * FLDP];   // V^T tile [h][t]
    __shared__ unsigned short Ps[64 * FLDP];   // P tile [qrow][t]

    const int b  = blockIdx.y;
    const int xx = blockIdx.x;                  // 0..63
    const int qt = (b < 4) ? xx : (63 - xx);    // complementary pairing for causal balance
    const int tid = threadIdx.x;
    const int wave = tid >> 6, lane = tid & 63, quad = lane >> 4, l16 = lane & 15;
    const int mrow = wave * 16;                 // wave's q-row offset in tile

    // stage Q tile [64][128] bf16
    const size_t qbase = ((size_t)b * T_ + (size_t)qt * 64) * H_;
    #pragma unroll
    for (int f = 0; f < 4; f++) {
        int g = f * 256 + tid;                  // 8-elem groups; 16 per row
        int row = g >> 4;
        int col = (g & 15) * 8;
        *(uint4*)&KQs[row * FLDQ + col] = *(const uint4*)(q + qbase + (size_t)row * H_ + col);
    }
    __syncthreads();
    // hoist Q A-frags (j-invariant): A[m=l16][k=quad*8+j]
    bf16x8 aq[4];
    #pragma unroll
    for (int kk = 0; kk < 4; kk++)
        aq[kk] = *(const bf16x8*)&KQs[(mrow + l16) * FLDQ + kk * 32 + quad * 8];

    float m_run[4], l_run[4];
    #pragma unroll
    for (int r = 0; r < 4; r++) { m_run[r] = -__builtin_inff(); l_run[r] = 0.f; }
    f32x4 o[8];
    #pragma unroll
    for (int nt = 0; nt < 8; nt++) o[nt] = (f32x4){0.f, 0.f, 0.f, 0.f};

    const float SC = 1.4426950408889634f * 0.08838834764831845f;  // log2(e)/sqrt(128)
    const int tq0 = qt * 64 + mrow + quad * 4;   // +r gives this lane's row's global t_q

    for (int j = 0; j <= qt; j++) {
        __syncthreads();   // prior iter's KQs/Vs reads done
        // stage K tile [64][128] into KQs (overwrites Q staging; aq is in regs)
        const size_t kb = ((size_t)b * T_ + (size_t)j * 64) * H_;
        #pragma unroll
        for (int f = 0; f < 4; f++) {
            int g = f * 256 + tid;
            int row = g >> 4;
            int col = (g & 15) * 8;
            *(uint4*)&KQs[row * FLDQ + col] = *(const uint4*)(kmat + kb + (size_t)row * H_ + col);
        }
        // stage V^T tile [128][64] (global already [h][t])
        const unsigned short* vb = vt + (size_t)b * H_ * T_ + (size_t)j * 64;
        #pragma unroll
        for (int f = 0; f < 4; f++) {
            int g = f * 256 + tid;                // 8 groups per row
            int row = g >> 3;
            int col = (g & 7) * 8;
            *(uint4*)&Vs[row * FLDP + col] = *(const uint4*)(vb + (size_t)row * T_ + col);
        }
        __syncthreads();

        // S = Q K^T : s[ni] covers cols ni*16..+16, rows quad*4+reg
        f32x4 s[4];
        #pragma unroll
        for (int ni = 0; ni < 4; ni++) s[ni] = (f32x4){0.f, 0.f, 0.f, 0.f};
        #pragma unroll
        for (int kk = 0; kk < 4; kk++) {
            #pragma unroll
            for (int ni = 0; ni < 4; ni++) {
                bf16x8 bk = *(const bf16x8*)&KQs[(ni * 16 + l16) * FLDQ + kk * 32 + quad * 8];
                s[ni] = __builtin_amdgcn_mfma_f32_16x16x32_bf16(aq[kk], bk, s[ni], 0, 0, 0);
            }
        }

        // scale (+causal mask on diagonal tile), base-2 online softmax
        const bool diag = (j == qt);
        #pragma unroll
        for (int ni = 0; ni < 4; ni++) {
            int tk = j * 64 + ni * 16 + l16;
            #pragma unroll
            for (int r = 0; r < 4; r++) {
                float v = s[ni][r] * SC;
                if (diag && tk > tq0 + r) v = -__builtin_inff();
                s[ni][r] = v;
            }
        }
        float mx[4];
        #pragma unroll
        for (int r = 0; r < 4; r++)
            mx[r] = fmaxf(fmaxf(s[0][r], s[1][r]), fmaxf(s[2][r], s[3][r]));
        #pragma unroll
        for (int off = 1; off < 16; off <<= 1)
            #pragma unroll
            for (int r = 0; r < 4; r++)
                mx[r] = fmaxf(mx[r], __shfl_xor(mx[r], off));
        float alpha[4];
        #pragma unroll
        for (int r = 0; r < 4; r++) {
            float mn = fmaxf(m_run[r], mx[r]);
            alpha[r] = exp2f(m_run[r] - mn);
            m_run[r] = mn;
        }
        float rs[4] = {0.f, 0.f, 0.f, 0.f};
        #pragma unroll
        for (int ni = 0; ni < 4; ni++)
            #pragma unroll
            for (int r = 0; r < 4; r++) {
                float p = exp2f(s[ni][r] - m_run[r]);   // masked -> exp2(-inf)=0
                s[ni][r] = p;
                rs[r] += p;
            }
        #pragma unroll
        for (int off = 1; off < 16; off <<= 1)
            #pragma unroll
            for (int r = 0; r < 4; r++)
                rs[r] += __shfl_xor(rs[r], off);
        #pragma unroll
        for (int r = 0; r < 4; r++)
            l_run[r] = l_run[r] * alpha[r] + rs[r];

        // P (C-layout) -> LDS (A-layout source). Each wave touches only its own 16 rows.
        #pragma unroll
        for (int ni = 0; ni < 4; ni++)
            #pragma unroll
            for (int r = 0; r < 4; r++)
                Ps[(mrow + quad * 4 + r) * FLDP + ni * 16 + l16] = f2bf(s[ni][r]);
        // rescale O
        #pragma unroll
        for (int nt = 0; nt < 8; nt++)
            #pragma unroll
            for (int r = 0; r < 4; r++)
                o[nt][r] *= alpha[r];

        // within-wave LDS write->read ordering (cross-lane, same wave)
        asm volatile("s_waitcnt lgkmcnt(0)" ::: "memory");

        // O += P V : A from Ps, B from Vs (V^T layout)
        #pragma unroll
        for (int ks = 0; ks < 2; ks++) {
            bf16x8 ap = *(const bf16x8*)&Ps[(mrow + l16) * FLDP + ks * 32 + quad * 8];
            #pragma unroll
            for (int nt = 0; nt < 8; nt++) {
                bf16x8 bv = *(const bf16x8*)&Vs[(nt * 16 + l16) * FLDP + ks * 32 + quad * 8];
                o[nt] = __builtin_amdgcn_mfma_f32_16x16x32_bf16(ap, bv, o[nt], 0, 0, 0);
            }
        }
    }

    // epilogue: out fp32 [b][t][h]
    #pragma unroll
    for (int r = 0; r < 4; r++) {
        float inv = 1.0f / l_run[r];
        size_t row = (size_t)b * T_ + (size_t)qt * 64 + mrow + quad * 4 + r;
        #pragma unroll
        for (int nt = 0; nt < 8; nt++)
            out[row * H_ + nt * 16 + l16] = o[nt][r] * inv;
    }
}

extern "C" void kernel_launch(void* const* d_in, const int* in_sizes, int n_in,
                              void* d_out, int out_size, void* d_ws, size_t ws_size,
                              hipStream_t stream) {
    const float* x  = (const float*)d_in[0];
    const float* Wq = (const float*)d_in[1];
    const float* Wk = (const float*)d_in[2];
    const float* Wv = (const float*)d_in[3];
    float* out = (float*)d_out;

    unsigned short* ws  = (unsigned short*)d_ws;
    const size_t nqkv   = (size_t)B_ * T_ * H_;          // 4.19M elems each
    unsigned short* qb  = ws;
    unsigned short* kb  = qb + nqkv;
    unsigned short* vtb = kb + nqkv;
    unsigned short* wt  = vtb + nqkv;                    // 3*128*1024

    wt_kernel<<<dim3((3 * C_ * H_) / 256), dim3(256), 0, stream>>>(Wq, Wk, Wv, wt);
    proj_kernel<<<dim3(3, (B_ * T_) / 128), dim3(256), 0, stream>>>(x, wt, qb, kb, vtb);
    flash_kernel<<<dim3(T_ / 64, B_), dim3(256), 0, stream>>>(qb, kb, vtb, out);
}